// Round 1
// baseline (805.720 us; speedup 1.0000x reference)
//
#include <hip/hip_runtime.h>
#include <hip/hip_bf16.h>

// out[i] = x[i] - max(ceil(x[i]), 1.0f)
// Pure streaming elementwise: HBM-bound. float4 vectorized (16 B/lane).

__global__ __launch_bounds__(256) void recur_kernel_vec4(const float4* __restrict__ x,
                                                         float4* __restrict__ out,
                                                         int n4) {
    int i = blockIdx.x * blockDim.x + threadIdx.x;
    if (i < n4) {
        float4 v = x[i];
        float4 r;
        r.x = v.x - fmaxf(ceilf(v.x), 1.0f);
        r.y = v.y - fmaxf(ceilf(v.y), 1.0f);
        r.z = v.z - fmaxf(ceilf(v.z), 1.0f);
        r.w = v.w - fmaxf(ceilf(v.w), 1.0f);
        out[i] = r;
    }
}

// Tail kernel in case n % 4 != 0 (not expected here: n = 2^27).
__global__ __launch_bounds__(64) void recur_kernel_tail(const float* __restrict__ x,
                                                        float* __restrict__ out,
                                                        int start, int n) {
    int i = start + blockIdx.x * blockDim.x + threadIdx.x;
    if (i < n) {
        float v = x[i];
        out[i] = v - fmaxf(ceilf(v), 1.0f);
    }
}

extern "C" void kernel_launch(void* const* d_in, const int* in_sizes, int n_in,
                              void* d_out, int out_size, void* d_ws, size_t ws_size,
                              hipStream_t stream) {
    const float* x = (const float*)d_in[0];
    float* out = (float*)d_out;
    int n = in_sizes[0];

    int n4 = n / 4;
    if (n4 > 0) {
        int threads = 256;
        int blocks = (n4 + threads - 1) / threads;
        recur_kernel_vec4<<<blocks, threads, 0, stream>>>(
            (const float4*)x, (float4*)out, n4);
    }
    int rem = n - n4 * 4;
    if (rem > 0) {
        recur_kernel_tail<<<1, 64, 0, stream>>>(x, out, n4 * 4, n);
    }
}